// Round 1
// baseline (1109.009 us; speedup 1.0000x reference)
//
#include <hip/hip_runtime.h>
#include <cstddef>

#define TC 96          // channels
#define BM 64          // rows per tile
#define NT 256         // threads per block
#define AST 100        // edge A lds row stride (floats): 400B rows, 16B aligned, 2-way bank spread
#define XST 204        // node X lds row stride (816B, 16B aligned)
#define HST 100        // node H lds row stride

__device__ __forceinline__ float fsigmoid(float x) {
    return 1.0f / (1.0f + __expf(-x));
}

// ---------------------------------------------------------------------------
// Edge kernel: per 64-edge tile, compute both edge MLPs (attention + phi_x)
// as one register-tiled fp32 GEMM against virtual B = [Wa1 | Wx1] (96x192),
// then scatter attention-weighted messages and coordinate deltas.
// Thread map: tx = tid&15 owns 12 cols (tx<8 -> attention half, tx>=8 -> phi_x
// half), ty = tid>>4 owns 4 rows. acc[4][12].
// ---------------------------------------------------------------------------
__global__ __launch_bounds__(NT, 4)
void edge_kernel(const float* __restrict__ m_ji,
                 const int*   __restrict__ edge_idx,   // [2][E]
                 const float* __restrict__ coords,
                 const float* __restrict__ Wa1, const float* __restrict__ ba1,
                 const float* __restrict__ Wa2, const float* __restrict__ ba2,
                 const float* __restrict__ Wx1, const float* __restrict__ bx1,
                 const float* __restrict__ Wx2, const float* __restrict__ bx2,
                 float* __restrict__ m_acc,       // ws accumulator [N][96] (zeroed)
                 float* __restrict__ out_coords,  // d_out coords (pre-seeded with coords)
                 float* __restrict__ out_att,     // d_out attention [E]
                 int E)
{
    __shared__ float A[BM][AST];
    __shared__ float s_att[BM];
    __shared__ float s_phx[BM];
    __shared__ int   s_recv[BM];
    __shared__ int   s_send[BM];

    const int tid  = threadIdx.x;
    const int e0   = blockIdx.x * BM;
    const int rows = (E - e0 < BM) ? (E - e0) : BM;

    if (tid < BM) {
        const int e = (tid < rows) ? (e0 + tid) : (E - 1);
        s_recv[tid] = edge_idx[e];
        s_send[tid] = edge_idx[E + e];
    }
    // stage m tile (row-major, vectorized, coalesced)
    for (int i4 = tid; i4 < BM * (TC / 4); i4 += NT) {
        const int r  = i4 / (TC / 4);
        const int c4 = i4 % (TC / 4);
        const int er = (r < rows) ? (e0 + r) : (E - 1);
        const float4 v = *reinterpret_cast<const float4*>(m_ji + (size_t)er * TC + c4 * 4);
        *reinterpret_cast<float4*>(&A[r][c4 * 4]) = v;
    }
    __syncthreads();

    const int tx = tid & 15;
    const int ty = tid >> 4;
    const int r0 = ty * 4;
    const bool isAtt = (tx < 8);
    const float* __restrict__ Bp = isAtt ? (Wa1 + tx * 12) : (Wx1 + (tx - 8) * 12);

    float acc[4][12];
    #pragma unroll
    for (int q = 0; q < 4; ++q) {
        #pragma unroll
        for (int j = 0; j < 12; ++j) acc[q][j] = 0.0f;
    }

    #pragma unroll 2
    for (int k = 0; k < TC; ++k) {
        const float4 b0 = *reinterpret_cast<const float4*>(Bp + (size_t)k * TC + 0);
        const float4 b1 = *reinterpret_cast<const float4*>(Bp + (size_t)k * TC + 4);
        const float4 b2 = *reinterpret_cast<const float4*>(Bp + (size_t)k * TC + 8);
        const float bv[12] = {b0.x, b0.y, b0.z, b0.w,
                              b1.x, b1.y, b1.z, b1.w,
                              b2.x, b2.y, b2.z, b2.w};
        const float a0 = A[r0 + 0][k];
        const float a1 = A[r0 + 1][k];
        const float a2 = A[r0 + 2][k];
        const float a3 = A[r0 + 3][k];
        #pragma unroll
        for (int j = 0; j < 12; ++j) {
            acc[0][j] = fmaf(a0, bv[j], acc[0][j]);
            acc[1][j] = fmaf(a1, bv[j], acc[1][j]);
            acc[2][j] = fmaf(a2, bv[j], acc[2][j]);
            acc[3][j] = fmaf(a3, bv[j], acc[3][j]);
        }
    }

    // epilogue: bias + SiLU + dot with layer-2 weight column
    const float* __restrict__ b1p = isAtt ? (ba1 + tx * 12) : (bx1 + (tx - 8) * 12);
    const float* __restrict__ w2p = isAtt ? (Wa2 + tx * 12) : (Wx2 + (tx - 8) * 12);
    float b1v[12], w2v[12];
    #pragma unroll
    for (int j = 0; j < 12; ++j) { b1v[j] = b1p[j]; w2v[j] = w2p[j]; }

    float red[4];
    #pragma unroll
    for (int q = 0; q < 4; ++q) {
        float p = 0.0f;
        #pragma unroll
        for (int j = 0; j < 12; ++j) {
            const float h = acc[q][j] + b1v[j];
            p = fmaf(h * fsigmoid(h), w2v[j], p);
        }
        red[q] = p;
    }
    // butterfly sum across the 8 lanes of each half (tx 0..7 att, tx 8..15 phi_x)
    #pragma unroll
    for (int m = 1; m <= 4; m <<= 1) {
        #pragma unroll
        for (int q = 0; q < 4; ++q) red[q] += __shfl_xor(red[q], m, 64);
    }
    if (tx == 0) {
        const float ba2v = ba2[0];
        #pragma unroll
        for (int q = 0; q < 4; ++q) s_att[r0 + q] = fsigmoid(red[q] + ba2v);
    }
    if (tx == 8) {
        const float bx2v = bx2[0];
        #pragma unroll
        for (int q = 0; q < 4; ++q) s_phx[r0 + q] = red[q] + bx2v;
    }
    __syncthreads();

    // attention output (coalesced)
    if (tid < rows) out_att[e0 + tid] = s_att[tid];

    // scatter attention-weighted messages into node accumulator
    for (int i = tid; i < rows * TC; i += NT) {
        const int r = i / TC;
        const int c = i - r * TC;
        atomicAdd(&m_acc[(size_t)s_recv[r] * TC + c], s_att[r] * A[r][c]);
    }

    // coordinate deltas
    if (tid < rows) {
        const int rcv = s_recv[tid];
        const int snd = s_send[tid];
        const float dx = coords[snd * 3 + 0] - coords[rcv * 3 + 0];
        const float dy = coords[snd * 3 + 1] - coords[rcv * 3 + 1];
        const float dz = coords[snd * 3 + 2] - coords[rcv * 3 + 2];
        const float nr = sqrtf(dx * dx + dy * dy + dz * dz);
        const float f  = s_phx[tid] / (nr + 1.0f);
        atomicAdd(&out_coords[rcv * 3 + 0], dx * f);
        atomicAdd(&out_coords[rcv * 3 + 1], dy * f);
        atomicAdd(&out_coords[rcv * 3 + 2], dz * f);
    }
}

// ---------------------------------------------------------------------------
// Node kernel: fused 2-layer node MLP with residual.
// X = [node_feats | m_i] (64 x 192) staged in LDS; H (64 x 96) staged in LDS.
// ---------------------------------------------------------------------------
__global__ __launch_bounds__(NT, 2)
void node_kernel(const float* __restrict__ node_feats,
                 const float* __restrict__ m_acc,
                 const float* __restrict__ Wn1, const float* __restrict__ bn1,
                 const float* __restrict__ Wn2, const float* __restrict__ bn2,
                 float* __restrict__ out_nf,
                 int N)
{
    __shared__ float X[BM][XST];
    __shared__ float H[BM][HST];

    const int tid = threadIdx.x;
    const int n0  = blockIdx.x * BM;

    for (int i4 = tid; i4 < BM * 48; i4 += NT) {
        const int r  = i4 / 48;
        const int c4 = i4 % 48;
        int node = n0 + r;
        if (node >= N) node = N - 1;
        float4 v;
        if (c4 < 24) v = *reinterpret_cast<const float4*>(node_feats + (size_t)node * TC + c4 * 4);
        else         v = *reinterpret_cast<const float4*>(m_acc + (size_t)node * TC + (c4 - 24) * 4);
        *reinterpret_cast<float4*>(&X[r][c4 * 4]) = v;
    }
    __syncthreads();

    const int tx = tid & 15;
    const int ty = tid >> 4;
    const int r0 = ty * 4;
    const int c0 = tx * 6;

    // layer 1: [64,192] @ [192,96]
    float acc[4][6];
    #pragma unroll
    for (int q = 0; q < 4; ++q) {
        #pragma unroll
        for (int j = 0; j < 6; ++j) acc[q][j] = 0.0f;
    }
    #pragma unroll 2
    for (int k = 0; k < 2 * TC; ++k) {
        const float2 b0 = *reinterpret_cast<const float2*>(Wn1 + (size_t)k * TC + c0 + 0);
        const float2 b1 = *reinterpret_cast<const float2*>(Wn1 + (size_t)k * TC + c0 + 2);
        const float2 b2 = *reinterpret_cast<const float2*>(Wn1 + (size_t)k * TC + c0 + 4);
        const float bv[6] = {b0.x, b0.y, b1.x, b1.y, b2.x, b2.y};
        const float a0 = X[r0 + 0][k];
        const float a1 = X[r0 + 1][k];
        const float a2 = X[r0 + 2][k];
        const float a3 = X[r0 + 3][k];
        #pragma unroll
        for (int j = 0; j < 6; ++j) {
            acc[0][j] = fmaf(a0, bv[j], acc[0][j]);
            acc[1][j] = fmaf(a1, bv[j], acc[1][j]);
            acc[2][j] = fmaf(a2, bv[j], acc[2][j]);
            acc[3][j] = fmaf(a3, bv[j], acc[3][j]);
        }
    }
    {
        float bnv[6];
        #pragma unroll
        for (int j = 0; j < 6; ++j) bnv[j] = bn1[c0 + j];
        #pragma unroll
        for (int q = 0; q < 4; ++q) {
            #pragma unroll
            for (int j = 0; j < 6; ++j) {
                const float h = acc[q][j] + bnv[j];
                H[r0 + q][c0 + j] = h * fsigmoid(h);
            }
        }
    }
    __syncthreads();

    // layer 2: [64,96] @ [96,96] + bias + residual
    float acc2[4][6];
    #pragma unroll
    for (int q = 0; q < 4; ++q) {
        #pragma unroll
        for (int j = 0; j < 6; ++j) acc2[q][j] = 0.0f;
    }
    #pragma unroll 2
    for (int k = 0; k < TC; ++k) {
        const float2 b0 = *reinterpret_cast<const float2*>(Wn2 + (size_t)k * TC + c0 + 0);
        const float2 b1 = *reinterpret_cast<const float2*>(Wn2 + (size_t)k * TC + c0 + 2);
        const float2 b2 = *reinterpret_cast<const float2*>(Wn2 + (size_t)k * TC + c0 + 4);
        const float bv[6] = {b0.x, b0.y, b1.x, b1.y, b2.x, b2.y};
        const float a0 = H[r0 + 0][k];
        const float a1 = H[r0 + 1][k];
        const float a2 = H[r0 + 2][k];
        const float a3 = H[r0 + 3][k];
        #pragma unroll
        for (int j = 0; j < 6; ++j) {
            acc2[0][j] = fmaf(a0, bv[j], acc2[0][j]);
            acc2[1][j] = fmaf(a1, bv[j], acc2[1][j]);
            acc2[2][j] = fmaf(a2, bv[j], acc2[2][j]);
            acc2[3][j] = fmaf(a3, bv[j], acc2[3][j]);
        }
    }
    {
        float bnv[6];
        #pragma unroll
        for (int j = 0; j < 6; ++j) bnv[j] = bn2[c0 + j];
        #pragma unroll
        for (int q = 0; q < 4; ++q) {
            const int node = n0 + r0 + q;
            if (node < N) {
                #pragma unroll
                for (int j = 0; j < 6; ++j) {
                    out_nf[(size_t)node * TC + c0 + j] = acc2[q][j] + bnv[j] + X[r0 + q][c0 + j];
                }
            }
        }
    }
}

extern "C" void kernel_launch(void* const* d_in, const int* in_sizes, int n_in,
                              void* d_out, int out_size, void* d_ws, size_t ws_size,
                              hipStream_t stream)
{
    const float* node_feats = (const float*)d_in[0];
    const float* coords     = (const float*)d_in[1];
    const float* m_ji       = (const float*)d_in[2];
    const int*   edge_idx   = (const int*)  d_in[3];
    const float* Wn1 = (const float*)d_in[4];
    const float* bn1 = (const float*)d_in[5];
    const float* Wn2 = (const float*)d_in[6];
    const float* bn2 = (const float*)d_in[7];
    const float* Wa1 = (const float*)d_in[8];
    const float* ba1 = (const float*)d_in[9];
    const float* Wa2 = (const float*)d_in[10];
    const float* ba2 = (const float*)d_in[11];
    const float* Wx1 = (const float*)d_in[12];
    const float* bx1 = (const float*)d_in[13];
    const float* Wx2 = (const float*)d_in[14];
    const float* bx2 = (const float*)d_in[15];

    const int N = in_sizes[0] / TC;
    const int E = in_sizes[2] / TC;

    float* out_nf     = (float*)d_out;
    float* out_coords = out_nf + (size_t)N * TC;
    float* out_att    = out_coords + (size_t)N * 3;
    float* m_acc      = (float*)d_ws;

    // zero message accumulator; seed output coords with input coords
    hipMemsetAsync(m_acc, 0, (size_t)N * TC * sizeof(float), stream);
    hipMemcpyAsync(out_coords, coords, (size_t)N * 3 * sizeof(float),
                   hipMemcpyDeviceToDevice, stream);

    const int edge_blocks = (E + BM - 1) / BM;
    edge_kernel<<<edge_blocks, NT, 0, stream>>>(
        m_ji, edge_idx, coords,
        Wa1, ba1, Wa2, ba2, Wx1, bx1, Wx2, bx2,
        m_acc, out_coords, out_att, E);

    const int node_blocks = (N + BM - 1) / BM;
    node_kernel<<<node_blocks, NT, 0, stream>>>(
        node_feats, m_acc, Wn1, bn1, Wn2, bn2, out_nf, N);
}